// Round 8
// baseline (332.071 us; speedup 1.0000x reference)
//
#include <hip/hip_runtime.h>
#include <hip/hip_bf16.h>

#define B_SZ   2
#define C_CH   64
#define NQ     8          // q/k channels (C/8)
#define NPIX   9216       // 96*96
#define QTILES 576        // NPIX/16
#define KPART  8          // key partitions, one per wave in a 512-thread block
#define KEYS_P 1152       // NPIX/KPART
#define NCHUNK 18         // 64 keys per chunk
#define PT_W   36         // dwords per P row (32 data + 4 pad; 144B stride)
#define PT_HALF (16*PT_W) // one parity buffer: 576 dwords
#define SM_F   1040       // per-partition combine floats: 1024 O + 16 L

typedef short bf16x8 __attribute__((ext_vector_type(8)));
typedef float f32x4  __attribute__((ext_vector_type(4)));

static __device__ __forceinline__ unsigned pack2bf(float a, float b){
    union { __hip_bfloat16 h; unsigned short us; } ca, cb;
    ca.h = __float2bfloat16(a); cb.h = __float2bfloat16(b);
    return (unsigned)ca.us | ((unsigned)cb.us << 16);
}

// ---------- fused prep: proj_v + proj_qk + gap in one dispatch ----------
__global__ __launch_bounds__(256) void prep_kernel(
    const float* __restrict__ x,
    const float* __restrict__ wq, const float* __restrict__ bq,
    const float* __restrict__ wk, const float* __restrict__ bk,
    const float* __restrict__ wv, const float* __restrict__ bv,
    __hip_bfloat16* __restrict__ qp, __hip_bfloat16* __restrict__ kp,
    __hip_bfloat16* __restrict__ vp, float* __restrict__ amean)
{
    const int blk = blockIdx.x, tid = threadIdx.x;
    if (blk < 288){
        int t  = blk*256 + tid;            // (b, cg, n)
        int n  = t % NPIX;
        int bc = t / NPIX;
        int b  = bc >> 2, cg = bc & 3;
        float acc[16];
#pragma unroll
        for (int o = 0; o < 16; ++o) acc[o] = bv[cg*16 + o];
        for (int ci = 0; ci < C_CH; ++ci){
            float xv = x[(size_t)(b*C_CH + ci)*NPIX + n];
#pragma unroll
            for (int o = 0; o < 16; ++o)
                acc[o] = fmaf(xv, wv[(cg*16 + o)*C_CH + ci], acc[o]);
        }
#pragma unroll
        for (int o = 0; o < 16; ++o)
            vp[(size_t)(b*C_CH + cg*16 + o)*NPIX + n] = __float2bfloat16(acc[o]);
    } else if (blk < 360){
        int t = (blk - 288)*256 + tid;     // (b,n)
        int b = t / NPIX, n = t - b*NPIX;
        float qa[NQ], ka[NQ];
#pragma unroll
        for (int o = 0; o < NQ; ++o){ qa[o] = bq[o]; ka[o] = bk[o]; }
        for (int c = 0; c < C_CH; ++c){
            float xv = x[(size_t)(b*C_CH + c)*NPIX + n];
#pragma unroll
            for (int o = 0; o < NQ; ++o){
                qa[o] = fmaf(xv, wq[o*C_CH + c], qa[o]);
                ka[o] = fmaf(xv, wk[o*C_CH + c], ka[o]);
            }
        }
#pragma unroll
        for (int o = 0; o < NQ; ++o){
            // fold log2(e) into q so softmax uses native exp2 (exact transform)
            qp[(size_t)t*NQ + o] = __float2bfloat16(qa[o] * 1.44269504f);
            kp[(size_t)t*NQ + o] = __float2bfloat16(ka[o]);
        }
    } else {
        int bc = blk - 360;                // (b*64+c)
        float s = 0.f;
        for (int i = tid; i < NPIX; i += 256) s += x[(size_t)bc*NPIX + i];
#pragma unroll
        for (int o = 32; o > 0; o >>= 1) s += __shfl_down(s, o, 64);
        __shared__ float red[4];
        if ((tid & 63) == 0) red[tid >> 6] = s;
        __syncthreads();
        if (tid == 0) amean[bc] = (red[0] + red[1] + red[2] + red[3]) * (1.f / (float)NPIX);
    }
}

// ---------- SE branch: 2x (linear+BN+relu) on GAP output ----------
__global__ void se_kernel(const float* __restrict__ amean,
                          const float* w1, const float* b1,
                          const float* n1w, const float* n1b,
                          const float* n1m, const float* n1v,
                          const float* w2, const float* b2,
                          const float* n2w, const float* n2b,
                          const float* n2m, const float* n2v,
                          float* __restrict__ a2)
{
    __shared__ float a1s[B_SZ][NQ];
    int t = threadIdx.x;
    if (t < B_SZ * NQ){
        int b = t >> 3, r = t & 7;
        float s = b1[r];
        for (int c = 0; c < C_CH; ++c) s = fmaf(amean[b*C_CH + c], w1[r*C_CH + c], s);
        s = (s - n1m[r]) * (n1w[r] * rsqrtf(n1v[r] + 1e-5f)) + n1b[r];
        a1s[b][r] = fmaxf(s, 0.f);
    }
    __syncthreads();
    {
        int b = t >> 6, c = t & 63;
        float s = b2[c];
#pragma unroll
        for (int r = 0; r < NQ; ++r) s = fmaf(a1s[b][r], w2[c*NQ + r], s);
        s = (s - n2m[c]) * (n2w[c] * rsqrtf(n2v[c] + 1e-5f)) + n2b[c];
        a2[b*C_CH + c] = fmaxf(s, 0.f);
    }
}

// ---------- fused attention + combine + epilogue (8 waves = 8 key partitions) ----------
// Max-free softmax; S^T = K·Q^T via mfma; P = exp2(S) -> parity-buffered LDS -> B-frag;
// O^T += V^T·P^T; L via ones-A-frag MFMA. 32 waves/CU for latency hiding.
__global__ __launch_bounds__(512, 8) void flash_fused(
    const __hip_bfloat16* __restrict__ qp,
    const __hip_bfloat16* __restrict__ kp,
    const __hip_bfloat16* __restrict__ vp,
    const float* __restrict__ a2,
    const float* __restrict__ x,
    const float* __restrict__ gamma,
    const float* __restrict__ bnw, const float* __restrict__ bnb,
    const float* __restrict__ bnm, const float* __restrict__ bnv,
    float* __restrict__ out)
{
    __shared__ __align__(16) unsigned lds[KPART*2*PT_HALF];  // 36864 B: P bufs / combine overlay

    const int qt = blockIdx.x, b = blockIdx.y;
    const int p  = threadIdx.x >> 6;     // wave = key partition [0,8)
    const int l  = threadIdx.x & 63;
    const int lq = l & 15;               // query column
    const int lg = l >> 4;               // lane group
    unsigned* pt = lds + p*(2*PT_HALF);  // this wave's two parity P buffers

    bf16x8 zf = {0,0,0,0,0,0,0,0};
    bf16x8 qfrag = zf;    // B-operand: B[d = lg*8+j][n = lq]
    if (lg == 0)
        qfrag = *reinterpret_cast<const bf16x8*>(qp + (size_t)(b*NPIX + qt*16 + lq) * NQ);

    bf16x8 ones;          // bf16 1.0 x8 — constant A-frag for the L-denominator MFMA
#pragma unroll
    for (int i = 0; i < 8; ++i) ones[i] = (short)0x3F80;

    f32x4 Of[4];
#pragma unroll
    for (int i = 0; i < 4; ++i) Of[i] = (f32x4){0.f, 0.f, 0.f, 0.f};
    f32x4 Lf = (f32x4){0.f, 0.f, 0.f, 0.f};

    for (int ch = 0; ch < NCHUNK; ++ch){
        const int j0 = p*KEYS_P + ch*64;
        unsigned* ptb = pt + (ch & 1)*PT_HALF;

        // --- K fragments (lane-group 0 holds the real K-dim) ---
        bf16x8 kf[4];
#pragma unroll
        for (int jt = 0; jt < 4; ++jt){
            kf[jt] = zf;
            if (lg == 0)
                kf[jt] = *reinterpret_cast<const bf16x8*>(kp + (size_t)(b*NPIX + j0 + jt*16 + lq) * NQ);
        }
        // --- S^T = K·Q^T : Sf[jt] rows = keys j0+jt*16+4*lg+r, col = query lq ---
        f32x4 Sf[4];
#pragma unroll
        for (int jt = 0; jt < 4; ++jt)
            Sf[jt] = __builtin_amdgcn_mfma_f32_16x16x32_bf16(kf[jt], qfrag, (f32x4){0.f,0.f,0.f,0.f}, 0, 0, 0);

        // --- P = exp2(S) (q pre-scaled), pack key pairs, store to parity buffer ---
#pragma unroll
        for (int jt = 0; jt < 4; ++jt){
            unsigned lo = pack2bf(exp2f(Sf[jt][0]), exp2f(Sf[jt][1]));
            unsigned hi = pack2bf(exp2f(Sf[jt][2]), exp2f(Sf[jt][3]));
            *reinterpret_cast<unsigned long long*>(&ptb[lq*PT_W + jt*8 + lg*2]) =
                (unsigned long long)lo | ((unsigned long long)hi << 32);
        }
        // --- O^T += V^T·P^T ; L += ones·P^T ---
#pragma unroll
        for (int kc = 0; kc < 2; ++kc){
            bf16x8 pf = *reinterpret_cast<const bf16x8*>(&ptb[lq*PT_W + kc*16 + lg*4]);
#pragma unroll
            for (int ct = 0; ct < 4; ++ct){
                bf16x8 vf = *reinterpret_cast<const bf16x8*>(
                    vp + (size_t)(b*C_CH + ct*16 + lq)*NPIX + (j0 + kc*32 + lg*8));
                Of[ct] = __builtin_amdgcn_mfma_f32_16x16x32_bf16(vf, pf, Of[ct], 0, 0, 0);
            }
            Lf = __builtin_amdgcn_mfma_f32_16x16x32_bf16(ones, pf, Lf, 0, 0, 0);
        }
    }

    // --- stage partials (overlays P buffers: barrier first) ---
    __syncthreads();
    float* sm = reinterpret_cast<float*>(lds);
#pragma unroll
    for (int ct = 0; ct < 4; ++ct)
#pragma unroll
        for (int r = 0; r < 4; ++r) sm[p*SM_F + (ct*4 + r)*64 + l] = Of[ct][r];
    if (l < 16) sm[p*SM_F + 1024 + l] = Lf[0];   // L(query lq), rows replicated
    __syncthreads();

    // --- combine 8 partitions + epilogue: out = x*(1+a2) + BN(gamma*O/L) ---
    {
        float L = 0.f;
#pragma unroll
        for (int q = 0; q < KPART; ++q) L += sm[q*SM_F + 1024 + lq];
        float invL = 1.f / L;
        float gam  = gamma[0];
        int n = qt*16 + lq;
        const int row0 = threadIdx.x >> 6;    // [0,8): two output rows per thread
#pragma unroll
        for (int h = 0; h < 2; ++h){
            int row = row0 + h*8;             // (ct*4 + r) in [0,16)
            float O = 0.f;
#pragma unroll
            for (int q = 0; q < KPART; ++q) O += sm[q*SM_F + row*64 + l];
            int c = (row >> 2)*16 + lg*4 + (row & 3);
            float pam = gam * O * invL;
            pam = (pam - bnm[c]) * (bnw[c] * rsqrtf(bnv[c] + 1e-5f)) + bnb[c];
            float xv = x[(size_t)(b*C_CH + c)*NPIX + n];
            out[(size_t)(b*C_CH + c)*NPIX + n] = fmaf(xv, a2[b*C_CH + c], xv + pam);
        }
    }
}

extern "C" void kernel_launch(void* const* d_in, const int* in_sizes, int n_in,
                              void* d_out, int out_size, void* d_ws, size_t ws_size,
                              hipStream_t stream)
{
    const float* x     = (const float*)d_in[0];
    const float* wq    = (const float*)d_in[1];
    const float* bq    = (const float*)d_in[2];
    const float* wk    = (const float*)d_in[3];
    const float* bk    = (const float*)d_in[4];
    const float* wv    = (const float*)d_in[5];
    const float* bv    = (const float*)d_in[6];
    const float* gamma = (const float*)d_in[7];
    const float* bnw   = (const float*)d_in[8];
    const float* bnb   = (const float*)d_in[9];
    const float* bnm   = (const float*)d_in[10];
    const float* bnv   = (const float*)d_in[11];
    const float* sw1   = (const float*)d_in[12];
    const float* sb1   = (const float*)d_in[13];
    const float* s1w   = (const float*)d_in[14];
    const float* s1b   = (const float*)d_in[15];
    const float* s1m   = (const float*)d_in[16];
    const float* s1v   = (const float*)d_in[17];
    const float* sw2   = (const float*)d_in[18];
    const float* sb2   = (const float*)d_in[19];
    const float* s2w   = (const float*)d_in[20];
    const float* s2b   = (const float*)d_in[21];
    const float* s2m   = (const float*)d_in[22];
    const float* s2v   = (const float*)d_in[23];

    size_t off = 0;
    auto give = [&](size_t bytes) -> void* {
        void* r = (char*)d_ws + off;
        off += (bytes + 255) & ~(size_t)255;
        return r;
    };
    __hip_bfloat16* qp = (__hip_bfloat16*)give((size_t)B_SZ*NPIX*NQ*2);
    __hip_bfloat16* kp = (__hip_bfloat16*)give((size_t)B_SZ*NPIX*NQ*2);
    __hip_bfloat16* vp = (__hip_bfloat16*)give((size_t)B_SZ*C_CH*NPIX*2);
    float* amean = (float*)give((size_t)B_SZ*C_CH*4);
    float* a2    = (float*)give((size_t)B_SZ*C_CH*4);

    prep_kernel<<<dim3(488), dim3(256), 0, stream>>>(x, wq, bq, wk, bk, wv, bv,
                                                     qp, kp, vp, amean);
    se_kernel<<<dim3(1), dim3(128), 0, stream>>>(amean, sw1, sb1, s1w, s1b, s1m, s1v,
                                                 sw2, sb2, s2w, s2b, s2m, s2v, a2);
    flash_fused<<<dim3(QTILES, B_SZ), dim3(512), 0, stream>>>(qp, kp, vp, a2, x, gamma,
                                                              bnw, bnb, bnm, bnv,
                                                              (float*)d_out);
}

// Round 9
// 238.831 us; speedup vs baseline: 1.3904x; 1.3904x over previous
//
#include <hip/hip_runtime.h>
#include <hip/hip_bf16.h>

#define B_SZ   2
#define C_CH   64
#define NQ     8          // q/k channels (C/8)
#define NPIX   9216       // 96*96
#define NJC    288        // NPIX/32 key 32-chunks per batch
#define QTILES 576        // NPIX/16
#define KPART  4          // key partitions, one per wave in a block
#define KEYS_P 2304       // NPIX/KPART
#define NCHUNK 36         // 64 keys per chunk
#define PT_W   36         // dwords per P row (32 data + 4 pad; 144B stride)
#define PT_HALF (16*PT_W) // one parity buffer: 576 dwords
#define SM_F   1040       // per-partition combine floats: 1024 O + 16 L

typedef short bf16x8 __attribute__((ext_vector_type(8)));
typedef float f32x4  __attribute__((ext_vector_type(4)));

static __device__ __forceinline__ unsigned pack2bf(float a, float b){
    union { __hip_bfloat16 h; unsigned short us; } ca, cb;
    ca.h = __float2bfloat16(a); cb.h = __float2bfloat16(b);
    return (unsigned)ca.us | ((unsigned)cb.us << 16);
}

// ---------- fused prep: proj_v + proj_qk + gap in one dispatch ----------
// V written PRE-SWIZZLED into MFMA-A-fragment order:
//   vswz element ((b*NJC + n/32)*4 + cg)*512 + o*32 + (n&31)  = V[b][cg*16+o][n]
// so a flash V-load is one contiguous 1KB per wave (16 sequential cache lines,
// distinct L1 sets) instead of 16 lines at 18KB stride (2-set thrash).
__global__ __launch_bounds__(256) void prep_kernel(
    const float* __restrict__ x,
    const float* __restrict__ wq, const float* __restrict__ bq,
    const float* __restrict__ wk, const float* __restrict__ bk,
    const float* __restrict__ wv, const float* __restrict__ bv,
    __hip_bfloat16* __restrict__ qp, __hip_bfloat16* __restrict__ kp,
    __hip_bfloat16* __restrict__ vswz, float* __restrict__ amean)
{
    const int blk = blockIdx.x, tid = threadIdx.x;
    if (blk < 288){
        int t  = blk*256 + tid;            // (b, cg, n)
        int n  = t % NPIX;
        int bc = t / NPIX;
        int b  = bc >> 2, cg = bc & 3;
        float acc[16];
#pragma unroll
        for (int o = 0; o < 16; ++o) acc[o] = bv[cg*16 + o];
        for (int ci = 0; ci < C_CH; ++ci){
            float xv = x[(size_t)(b*C_CH + ci)*NPIX + n];
#pragma unroll
            for (int o = 0; o < 16; ++o)
                acc[o] = fmaf(xv, wv[(cg*16 + o)*C_CH + ci], acc[o]);
        }
        size_t base = ((size_t)((b*NJC + (n >> 5))*4 + cg))*512 + (n & 31);
#pragma unroll
        for (int o = 0; o < 16; ++o)
            vswz[base + o*32] = __float2bfloat16(acc[o]);
    } else if (blk < 360){
        int t = (blk - 288)*256 + tid;     // (b,n)
        int b = t / NPIX, n = t - b*NPIX;
        float qa[NQ], ka[NQ];
#pragma unroll
        for (int o = 0; o < NQ; ++o){ qa[o] = bq[o]; ka[o] = bk[o]; }
        for (int c = 0; c < C_CH; ++c){
            float xv = x[(size_t)(b*C_CH + c)*NPIX + n];
#pragma unroll
            for (int o = 0; o < NQ; ++o){
                qa[o] = fmaf(xv, wq[o*C_CH + c], qa[o]);
                ka[o] = fmaf(xv, wk[o*C_CH + c], ka[o]);
            }
        }
#pragma unroll
        for (int o = 0; o < NQ; ++o){
            // fold log2(e) into q so softmax uses native exp2 (exact transform)
            qp[(size_t)t*NQ + o] = __float2bfloat16(qa[o] * 1.44269504f);
            kp[(size_t)t*NQ + o] = __float2bfloat16(ka[o]);
        }
    } else {
        int bc = blk - 360;                // (b*64+c)
        float s = 0.f;
        for (int i = tid; i < NPIX; i += 256) s += x[(size_t)bc*NPIX + i];
#pragma unroll
        for (int o = 32; o > 0; o >>= 1) s += __shfl_down(s, o, 64);
        __shared__ float red[4];
        if ((tid & 63) == 0) red[tid >> 6] = s;
        __syncthreads();
        if (tid == 0) amean[bc] = (red[0] + red[1] + red[2] + red[3]) * (1.f / (float)NPIX);
    }
}

// ---------- SE branch: 2x (linear+BN+relu) on GAP output ----------
__global__ void se_kernel(const float* __restrict__ amean,
                          const float* w1, const float* b1,
                          const float* n1w, const float* n1b,
                          const float* n1m, const float* n1v,
                          const float* w2, const float* b2,
                          const float* n2w, const float* n2b,
                          const float* n2m, const float* n2v,
                          float* __restrict__ a2)
{
    __shared__ float a1s[B_SZ][NQ];
    int t = threadIdx.x;
    if (t < B_SZ * NQ){
        int b = t >> 3, r = t & 7;
        float s = b1[r];
        for (int c = 0; c < C_CH; ++c) s = fmaf(amean[b*C_CH + c], w1[r*C_CH + c], s);
        s = (s - n1m[r]) * (n1w[r] * rsqrtf(n1v[r] + 1e-5f)) + n1b[r];
        a1s[b][r] = fmaxf(s, 0.f);
    }
    __syncthreads();
    {
        int b = t >> 6, c = t & 63;
        float s = b2[c];
#pragma unroll
        for (int r = 0; r < NQ; ++r) s = fmaf(a1s[b][r], w2[c*NQ + r], s);
        s = (s - n2m[c]) * (n2w[c] * rsqrtf(n2v[c] + 1e-5f)) + n2b[c];
        a2[b*C_CH + c] = fmaxf(s, 0.f);
    }
}

// ---------- fused attention + combine + epilogue ----------
// r7 structure; V reads now hit the swizzled fragment-contiguous layout.
__global__ __launch_bounds__(256, 4) void flash_fused(
    const __hip_bfloat16* __restrict__ qp,
    const __hip_bfloat16* __restrict__ kp,
    const __hip_bfloat16* __restrict__ vswz,
    const float* __restrict__ a2,
    const float* __restrict__ x,
    const float* __restrict__ gamma,
    const float* __restrict__ bnw, const float* __restrict__ bnb,
    const float* __restrict__ bnm, const float* __restrict__ bnv,
    float* __restrict__ out)
{
    __shared__ __align__(16) unsigned lds[KPART*2*PT_HALF];   // 18432 B: P bufs / combine overlay

    const int qt = blockIdx.x, b = blockIdx.y;
    const int p  = threadIdx.x >> 6;     // wave = key partition
    const int l  = threadIdx.x & 63;
    const int lq = l & 15;               // query column
    const int lg = l >> 4;               // lane group
    unsigned* pt = lds + p*(2*PT_HALF);  // this wave's two parity P buffers
    const int vlane = lq*32 + lg*8;      // bf16 offset of this lane's V frag in a 1KB tile

    bf16x8 zf = {0,0,0,0,0,0,0,0};
    bf16x8 qfrag = zf;    // B-operand: B[d = lg*8+j][n = lq]
    if (lg == 0)
        qfrag = *reinterpret_cast<const bf16x8*>(qp + (size_t)(b*NPIX + qt*16 + lq) * NQ);

    bf16x8 ones;          // bf16 1.0 x8 — constant A-frag for the L-denominator MFMA
#pragma unroll
    for (int i = 0; i < 8; ++i) ones[i] = (short)0x3F80;

    f32x4 Of[4];
#pragma unroll
    for (int i = 0; i < 4; ++i) Of[i] = (f32x4){0.f, 0.f, 0.f, 0.f};
    f32x4 Lf = (f32x4){0.f, 0.f, 0.f, 0.f};

    for (int ch = 0; ch < NCHUNK; ++ch){
        const int j0  = p*KEYS_P + ch*64;
        const int jcb = b*NJC + (j0 >> 5);          // global 32-key chunk index
        unsigned* ptb = pt + (ch & 1)*PT_HALF;

        // --- K fragments (lane-group 0 holds the real K-dim) ---
        bf16x8 kf[4];
#pragma unroll
        for (int jt = 0; jt < 4; ++jt){
            kf[jt] = zf;
            if (lg == 0)
                kf[jt] = *reinterpret_cast<const bf16x8*>(kp + (size_t)(b*NPIX + j0 + jt*16 + lq) * NQ);
        }
        // --- V fragments: contiguous 1KB per (kc,ct) tile ---
        bf16x8 vf[2][4];
#pragma unroll
        for (int kc = 0; kc < 2; ++kc)
#pragma unroll
            for (int ct = 0; ct < 4; ++ct)
                vf[kc][ct] = *reinterpret_cast<const bf16x8*>(
                    vswz + ((size_t)((jcb + kc)*4 + ct))*512 + vlane);

        // --- S^T = K·Q^T : Sf[jt] rows = keys j0+jt*16+4*lg+r, col = query lq ---
        f32x4 Sf[4];
#pragma unroll
        for (int jt = 0; jt < 4; ++jt)
            Sf[jt] = __builtin_amdgcn_mfma_f32_16x16x32_bf16(kf[jt], qfrag, (f32x4){0.f,0.f,0.f,0.f}, 0, 0, 0);

        // --- P = exp2(S) (q pre-scaled), pack key pairs, store to parity buffer ---
#pragma unroll
        for (int jt = 0; jt < 4; ++jt){
            unsigned lo = pack2bf(exp2f(Sf[jt][0]), exp2f(Sf[jt][1]));
            unsigned hi = pack2bf(exp2f(Sf[jt][2]), exp2f(Sf[jt][3]));
            *reinterpret_cast<unsigned long long*>(&ptb[lq*PT_W + jt*8 + lg*2]) =
                (unsigned long long)lo | ((unsigned long long)hi << 32);
        }
        // --- O^T += V^T·P^T ; L += ones·P^T ---
#pragma unroll
        for (int kc = 0; kc < 2; ++kc){
            bf16x8 pf = *reinterpret_cast<const bf16x8*>(&ptb[lq*PT_W + kc*16 + lg*4]);
#pragma unroll
            for (int ct = 0; ct < 4; ++ct)
                Of[ct] = __builtin_amdgcn_mfma_f32_16x16x32_bf16(vf[kc][ct], pf, Of[ct], 0, 0, 0);
            Lf = __builtin_amdgcn_mfma_f32_16x16x32_bf16(ones, pf, Lf, 0, 0, 0);
        }
    }

    // --- stage partials (overlays P buffers: barrier first) ---
    __syncthreads();
    float* sm = reinterpret_cast<float*>(lds);
#pragma unroll
    for (int ct = 0; ct < 4; ++ct)
#pragma unroll
        for (int r = 0; r < 4; ++r) sm[p*SM_F + (ct*4 + r)*64 + l] = Of[ct][r];
    if (l < 16) sm[p*SM_F + 1024 + l] = Lf[0];   // L(query lq), rows replicated
    __syncthreads();

    // --- combine partitions + epilogue: out = x*(1+a2) + BN(gamma*O/L) ---
    {
        const int ct = threadIdx.x >> 6;   // each thread: 4 channels x 1 pixel
        float L = 0.f;
#pragma unroll
        for (int q = 0; q < KPART; ++q) L += sm[q*SM_F + 1024 + lq];
        float invL = 1.f / L;
        float gam  = gamma[0];
        int n = qt*16 + lq;
#pragma unroll
        for (int r = 0; r < 4; ++r){
            float O = 0.f;
#pragma unroll
            for (int q = 0; q < KPART; ++q) O += sm[q*SM_F + (ct*4 + r)*64 + l];
            int c = ct*16 + lg*4 + r;
            float pam = gam * O * invL;
            pam = (pam - bnm[c]) * (bnw[c] * rsqrtf(bnv[c] + 1e-5f)) + bnb[c];
            float xv = x[(size_t)(b*C_CH + c)*NPIX + n];
            out[(size_t)(b*C_CH + c)*NPIX + n] = fmaf(xv, a2[b*C_CH + c], xv + pam);
        }
    }
}

extern "C" void kernel_launch(void* const* d_in, const int* in_sizes, int n_in,
                              void* d_out, int out_size, void* d_ws, size_t ws_size,
                              hipStream_t stream)
{
    const float* x     = (const float*)d_in[0];
    const float* wq    = (const float*)d_in[1];
    const float* bq    = (const float*)d_in[2];
    const float* wk    = (const float*)d_in[3];
    const float* bk    = (const float*)d_in[4];
    const float* wv    = (const float*)d_in[5];
    const float* bv    = (const float*)d_in[6];
    const float* gamma = (const float*)d_in[7];
    const float* bnw   = (const float*)d_in[8];
    const float* bnb   = (const float*)d_in[9];
    const float* bnm   = (const float*)d_in[10];
    const float* bnv   = (const float*)d_in[11];
    const float* sw1   = (const float*)d_in[12];
    const float* sb1   = (const float*)d_in[13];
    const float* s1w   = (const float*)d_in[14];
    const float* s1b   = (const float*)d_in[15];
    const float* s1m   = (const float*)d_in[16];
    const float* s1v   = (const float*)d_in[17];
    const float* sw2   = (const float*)d_in[18];
    const float* sb2   = (const float*)d_in[19];
    const float* s2w   = (const float*)d_in[20];
    const float* s2b   = (const float*)d_in[21];
    const float* s2m   = (const float*)d_in[22];
    const float* s2v   = (const float*)d_in[23];

    size_t off = 0;
    auto give = [&](size_t bytes) -> void* {
        void* r = (char*)d_ws + off;
        off += (bytes + 255) & ~(size_t)255;
        return r;
    };
    __hip_bfloat16* qp   = (__hip_bfloat16*)give((size_t)B_SZ*NPIX*NQ*2);
    __hip_bfloat16* kp   = (__hip_bfloat16*)give((size_t)B_SZ*NPIX*NQ*2);
    __hip_bfloat16* vswz = (__hip_bfloat16*)give((size_t)B_SZ*C_CH*NPIX*2);
    float* amean = (float*)give((size_t)B_SZ*C_CH*4);
    float* a2    = (float*)give((size_t)B_SZ*C_CH*4);

    prep_kernel<<<dim3(488), dim3(256), 0, stream>>>(x, wq, bq, wk, bk, wv, bv,
                                                     qp, kp, vswz, amean);
    se_kernel<<<dim3(1), dim3(128), 0, stream>>>(amean, sw1, sb1, s1w, s1b, s1m, s1v,
                                                 sw2, sb2, s2w, s2b, s2m, s2v, a2);
    flash_fused<<<dim3(QTILES, B_SZ), dim3(256), 0, stream>>>(qp, kp, vswz, a2, x, gamma,
                                                              bnw, bnb, bnm, bnv,
                                                              (float*)d_out);
}

// Round 10
// 225.583 us; speedup vs baseline: 1.4721x; 1.0587x over previous
//
#include <hip/hip_runtime.h>
#include <hip/hip_bf16.h>

#define B_SZ   2
#define C_CH   64
#define NQ     8          // q/k channels (C/8)
#define NPIX   9216       // 96*96
#define NJC    288        // NPIX/32 key 32-chunks per batch
#define QTILES 576        // NPIX/16
#define KPART  4          // key partitions, one per wave in a block
#define KEYS_P 2304       // NPIX/KPART
#define NCHUNK 36         // 64 keys per chunk
#define PT_W   36         // dwords per P row (32 data + 4 pad; 144B stride)
#define PT_HALF (16*PT_W) // one parity buffer: 576 dwords
#define SM_F   1040       // per-partition combine floats: 1024 O + 16 L
#define NP4    2304       // NPIX/4

typedef short bf16x8 __attribute__((ext_vector_type(8)));
typedef float f32x4  __attribute__((ext_vector_type(4)));

static __device__ __forceinline__ unsigned pack2bf(float a, float b){
    union { __hip_bfloat16 h; unsigned short us; } ca, cb;
    ca.h = __float2bfloat16(a); cb.h = __float2bfloat16(b);
    return (unsigned)ca.us | ((unsigned)cb.us << 16);
}

// ---------- fused prep, short-chain/high-TLP mapping ----------
// blocks [0,1152):     proj_v  thread = (b, c, n4): 4 px, 1 channel
// blocks [1152,1440):  proj_qk thread = (b, o16, n4): 4 px, 1 of 16 q/k outputs
// blocks [1440,1568):  GAP
// V written PRE-SWIZZLED into MFMA-A-fragment order (1KB-contiguous wave tiles):
//   vswz[((b*NJC + n/32)*4 + c/16)*512 + (c&15)*32 + (n&31)] = V[b][c][n]
__global__ __launch_bounds__(256) void prep_kernel(
    const float* __restrict__ x,
    const float* __restrict__ wq, const float* __restrict__ bq,
    const float* __restrict__ wk, const float* __restrict__ bk,
    const float* __restrict__ wv, const float* __restrict__ bv,
    __hip_bfloat16* __restrict__ qp, __hip_bfloat16* __restrict__ kp,
    __hip_bfloat16* __restrict__ vswz, float* __restrict__ amean)
{
    const int blk = blockIdx.x, tid = threadIdx.x;
    if (blk < 1152){
        int t  = blk*256 + tid;            // (b, c, n4)
        int n  = (t % NP4) * 4;
        int c  = (t / NP4) & 63;           // wave-uniform (NP4 % 64 == 0)
        int b  = t / (NP4*64);
        float a0 = bv[c], a1 = a0, a2v = a0, a3 = a0;
        for (int ci = 0; ci < C_CH; ++ci){
            const float4 xv = *reinterpret_cast<const float4*>(
                x + (size_t)(b*C_CH + ci)*NPIX + n);
            float w = wv[c*C_CH + ci];
            a0 = fmaf(xv.x, w, a0); a1 = fmaf(xv.y, w, a1);
            a2v = fmaf(xv.z, w, a2v); a3 = fmaf(xv.w, w, a3);
        }
        size_t base = ((size_t)((b*NJC + (n >> 5))*4 + (c >> 4)))*512
                    + ((c & 15)*32) + (n & 31);
        unsigned long long wpk =
            (unsigned long long)pack2bf(a0, a1) |
            ((unsigned long long)pack2bf(a2v, a3) << 32);
        *reinterpret_cast<unsigned long long*>(vswz + base) = wpk;
    } else if (blk < 1440){
        int t  = (blk - 1152)*256 + tid;   // (b, o16, n4)
        int n  = (t % NP4) * 4;
        int o16= (t / NP4) & 15;           // wave-uniform; 0-7 => q, 8-15 => k
        int b  = t / (NP4*16);
        bool isq = (o16 < 8);
        int  o   = isq ? o16 : o16 - 8;
        const float* w = isq ? (wq + o*C_CH) : (wk + o*C_CH);
        float bias = isq ? bq[o] : bk[o];
        float a0 = bias, a1 = bias, a2v = bias, a3 = bias;
        for (int ci = 0; ci < C_CH; ++ci){
            const float4 xv = *reinterpret_cast<const float4*>(
                x + (size_t)(b*C_CH + ci)*NPIX + n);
            float wv_ = w[ci];
            a0 = fmaf(xv.x, wv_, a0); a1 = fmaf(xv.y, wv_, a1);
            a2v = fmaf(xv.z, wv_, a2v); a3 = fmaf(xv.w, wv_, a3);
        }
        if (isq){  // fold log2(e) so softmax uses native exp2
            a0 *= 1.44269504f; a1 *= 1.44269504f; a2v *= 1.44269504f; a3 *= 1.44269504f;
            __hip_bfloat16* q0 = qp + ((size_t)(b*NPIX + n))*NQ + o;
            q0[0] = __float2bfloat16(a0);  q0[8]  = __float2bfloat16(a1);
            q0[16] = __float2bfloat16(a2v); q0[24] = __float2bfloat16(a3);
        } else {
            __hip_bfloat16* k0 = kp + ((size_t)(b*NPIX + n))*NQ + o;
            k0[0] = __float2bfloat16(a0);  k0[8]  = __float2bfloat16(a1);
            k0[16] = __float2bfloat16(a2v); k0[24] = __float2bfloat16(a3);
        }
    } else {
        int bc = blk - 1440;               // (b*64+c)
        float s = 0.f;
        for (int i = tid; i < NPIX; i += 256) s += x[(size_t)bc*NPIX + i];
#pragma unroll
        for (int o = 32; o > 0; o >>= 1) s += __shfl_down(s, o, 64);
        __shared__ float red[4];
        if ((tid & 63) == 0) red[tid >> 6] = s;
        __syncthreads();
        if (tid == 0) amean[bc] = (red[0] + red[1] + red[2] + red[3]) * (1.f / (float)NPIX);
    }
}

// ---------- SE branch: 2x (linear+BN+relu) on GAP output ----------
__global__ void se_kernel(const float* __restrict__ amean,
                          const float* w1, const float* b1,
                          const float* n1w, const float* n1b,
                          const float* n1m, const float* n1v,
                          const float* w2, const float* b2,
                          const float* n2w, const float* n2b,
                          const float* n2m, const float* n2v,
                          float* __restrict__ a2)
{
    __shared__ float a1s[B_SZ][NQ];
    int t = threadIdx.x;
    if (t < B_SZ * NQ){
        int b = t >> 3, r = t & 7;
        float s = b1[r];
        for (int c = 0; c < C_CH; ++c) s = fmaf(amean[b*C_CH + c], w1[r*C_CH + c], s);
        s = (s - n1m[r]) * (n1w[r] * rsqrtf(n1v[r] + 1e-5f)) + n1b[r];
        a1s[b][r] = fmaxf(s, 0.f);
    }
    __syncthreads();
    {
        int b = t >> 6, c = t & 63;
        float s = b2[c];
#pragma unroll
        for (int r = 0; r < NQ; ++r) s = fmaf(a1s[b][r], w2[c*NQ + r], s);
        s = (s - n2m[c]) * (n2w[c] * rsqrtf(n2v[c] + 1e-5f)) + n2b[c];
        a2[b*C_CH + c] = fmaxf(s, 0.f);
    }
}

// ---------- fused attention + combine + epilogue (r9 structure, unchanged) ----------
__global__ __launch_bounds__(256, 4) void flash_fused(
    const __hip_bfloat16* __restrict__ qp,
    const __hip_bfloat16* __restrict__ kp,
    const __hip_bfloat16* __restrict__ vswz,
    const float* __restrict__ a2,
    const float* __restrict__ x,
    const float* __restrict__ gamma,
    const float* __restrict__ bnw, const float* __restrict__ bnb,
    const float* __restrict__ bnm, const float* __restrict__ bnv,
    float* __restrict__ out)
{
    __shared__ __align__(16) unsigned lds[KPART*2*PT_HALF];   // 18432 B: P bufs / combine overlay

    const int qt = blockIdx.x, b = blockIdx.y;
    const int p  = threadIdx.x >> 6;     // wave = key partition
    const int l  = threadIdx.x & 63;
    const int lq = l & 15;               // query column
    const int lg = l >> 4;               // lane group
    unsigned* pt = lds + p*(2*PT_HALF);  // this wave's two parity P buffers
    const int vlane = lq*32 + lg*8;      // bf16 offset of this lane's V frag in a 1KB tile

    bf16x8 zf = {0,0,0,0,0,0,0,0};
    bf16x8 qfrag = zf;    // B-operand: B[d = lg*8+j][n = lq]
    if (lg == 0)
        qfrag = *reinterpret_cast<const bf16x8*>(qp + (size_t)(b*NPIX + qt*16 + lq) * NQ);

    bf16x8 ones;          // bf16 1.0 x8 — constant A-frag for the L-denominator MFMA
#pragma unroll
    for (int i = 0; i < 8; ++i) ones[i] = (short)0x3F80;

    f32x4 Of[4];
#pragma unroll
    for (int i = 0; i < 4; ++i) Of[i] = (f32x4){0.f, 0.f, 0.f, 0.f};
    f32x4 Lf = (f32x4){0.f, 0.f, 0.f, 0.f};

    for (int ch = 0; ch < NCHUNK; ++ch){
        const int j0  = p*KEYS_P + ch*64;
        const int jcb = b*NJC + (j0 >> 5);          // global 32-key chunk index
        unsigned* ptb = pt + (ch & 1)*PT_HALF;

        // --- K fragments (lane-group 0 holds the real K-dim) ---
        bf16x8 kf[4];
#pragma unroll
        for (int jt = 0; jt < 4; ++jt){
            kf[jt] = zf;
            if (lg == 0)
                kf[jt] = *reinterpret_cast<const bf16x8*>(kp + (size_t)(b*NPIX + j0 + jt*16 + lq) * NQ);
        }
        // --- V fragments: contiguous 1KB per (kc,ct) tile ---
        bf16x8 vf[2][4];
#pragma unroll
        for (int kc = 0; kc < 2; ++kc)
#pragma unroll
            for (int ct = 0; ct < 4; ++ct)
                vf[kc][ct] = *reinterpret_cast<const bf16x8*>(
                    vswz + ((size_t)((jcb + kc)*4 + ct))*512 + vlane);

        // --- S^T = K·Q^T : Sf[jt] rows = keys j0+jt*16+4*lg+r, col = query lq ---
        f32x4 Sf[4];
#pragma unroll
        for (int jt = 0; jt < 4; ++jt)
            Sf[jt] = __builtin_amdgcn_mfma_f32_16x16x32_bf16(kf[jt], qfrag, (f32x4){0.f,0.f,0.f,0.f}, 0, 0, 0);

        // --- P = exp2(S) (q pre-scaled), pack key pairs, store to parity buffer ---
#pragma unroll
        for (int jt = 0; jt < 4; ++jt){
            unsigned lo = pack2bf(exp2f(Sf[jt][0]), exp2f(Sf[jt][1]));
            unsigned hi = pack2bf(exp2f(Sf[jt][2]), exp2f(Sf[jt][3]));
            *reinterpret_cast<unsigned long long*>(&ptb[lq*PT_W + jt*8 + lg*2]) =
                (unsigned long long)lo | ((unsigned long long)hi << 32);
        }
        // --- O^T += V^T·P^T ; L += ones·P^T ---
#pragma unroll
        for (int kc = 0; kc < 2; ++kc){
            bf16x8 pf = *reinterpret_cast<const bf16x8*>(&ptb[lq*PT_W + kc*16 + lg*4]);
#pragma unroll
            for (int ct = 0; ct < 4; ++ct)
                Of[ct] = __builtin_amdgcn_mfma_f32_16x16x32_bf16(vf[kc][ct], pf, Of[ct], 0, 0, 0);
            Lf = __builtin_amdgcn_mfma_f32_16x16x32_bf16(ones, pf, Lf, 0, 0, 0);
        }
    }

    // --- stage partials (overlays P buffers: barrier first) ---
    __syncthreads();
    float* sm = reinterpret_cast<float*>(lds);
#pragma unroll
    for (int ct = 0; ct < 4; ++ct)
#pragma unroll
        for (int r = 0; r < 4; ++r) sm[p*SM_F + (ct*4 + r)*64 + l] = Of[ct][r];
    if (l < 16) sm[p*SM_F + 1024 + l] = Lf[0];   // L(query lq), rows replicated
    __syncthreads();

    // --- combine partitions + epilogue: out = x*(1+a2) + BN(gamma*O/L) ---
    {
        const int ct = threadIdx.x >> 6;   // each thread: 4 channels x 1 pixel
        float L = 0.f;
#pragma unroll
        for (int q = 0; q < KPART; ++q) L += sm[q*SM_F + 1024 + lq];
        float invL = 1.f / L;
        float gam  = gamma[0];
        int n = qt*16 + lq;
#pragma unroll
        for (int r = 0; r < 4; ++r){
            float O = 0.f;
#pragma unroll
            for (int q = 0; q < KPART; ++q) O += sm[q*SM_F + (ct*4 + r)*64 + l];
            int c = ct*16 + lg*4 + r;
            float pam = gam * O * invL;
            pam = (pam - bnm[c]) * (bnw[c] * rsqrtf(bnv[c] + 1e-5f)) + bnb[c];
            float xv = x[(size_t)(b*C_CH + c)*NPIX + n];
            out[(size_t)(b*C_CH + c)*NPIX + n] = fmaf(xv, a2[b*C_CH + c], xv + pam);
        }
    }
}

extern "C" void kernel_launch(void* const* d_in, const int* in_sizes, int n_in,
                              void* d_out, int out_size, void* d_ws, size_t ws_size,
                              hipStream_t stream)
{
    const float* x     = (const float*)d_in[0];
    const float* wq    = (const float*)d_in[1];
    const float* bq    = (const float*)d_in[2];
    const float* wk    = (const float*)d_in[3];
    const float* bk    = (const float*)d_in[4];
    const float* wv    = (const float*)d_in[5];
    const float* bv    = (const float*)d_in[6];
    const float* gamma = (const float*)d_in[7];
    const float* bnw   = (const float*)d_in[8];
    const float* bnb   = (const float*)d_in[9];
    const float* bnm   = (const float*)d_in[10];
    const float* bnv   = (const float*)d_in[11];
    const float* sw1   = (const float*)d_in[12];
    const float* sb1   = (const float*)d_in[13];
    const float* s1w   = (const float*)d_in[14];
    const float* s1b   = (const float*)d_in[15];
    const float* s1m   = (const float*)d_in[16];
    const float* s1v   = (const float*)d_in[17];
    const float* sw2   = (const float*)d_in[18];
    const float* sb2   = (const float*)d_in[19];
    const float* s2w   = (const float*)d_in[20];
    const float* s2b   = (const float*)d_in[21];
    const float* s2m   = (const float*)d_in[22];
    const float* s2v   = (const float*)d_in[23];

    size_t off = 0;
    auto give = [&](size_t bytes) -> void* {
        void* r = (char*)d_ws + off;
        off += (bytes + 255) & ~(size_t)255;
        return r;
    };
    __hip_bfloat16* qp   = (__hip_bfloat16*)give((size_t)B_SZ*NPIX*NQ*2);
    __hip_bfloat16* kp   = (__hip_bfloat16*)give((size_t)B_SZ*NPIX*NQ*2);
    __hip_bfloat16* vswz = (__hip_bfloat16*)give((size_t)B_SZ*C_CH*NPIX*2);
    float* amean = (float*)give((size_t)B_SZ*C_CH*4);
    float* a2    = (float*)give((size_t)B_SZ*C_CH*4);

    prep_kernel<<<dim3(1568), dim3(256), 0, stream>>>(x, wq, bq, wk, bk, wv, bv,
                                                      qp, kp, vswz, amean);
    se_kernel<<<dim3(1), dim3(128), 0, stream>>>(amean, sw1, sb1, s1w, s1b, s1m, s1v,
                                                 sw2, sb2, s2w, s2b, s2m, s2v, a2);
    flash_fused<<<dim3(QTILES, B_SZ), dim3(256), 0, stream>>>(qp, kp, vswz, a2, x, gamma,
                                                              bnw, bnb, bnm, bnv,
                                                              (float*)d_out);
}